// Round 16
// baseline (105.716 us; speedup 1.0000x reference)
//
#include <hip/hip_runtime.h>
#include <math.h>

// Problem constants (B=2, C=128, N=256, H=64, CH=256)
#define BB 2
#define CC 128
#define NN 256
#define HH 64
#define CHX 256
#define COLS 768           // 3*N flattened (v,n) columns
#define NEG_ATTN 0.2f
#define NEG_FFN 0.1f

typedef __attribute__((ext_vector_type(8))) short short8b;   // 8 bf16 (4 VGPRs)
typedef __attribute__((ext_vector_type(4))) float f32x4;

__device__ __forceinline__ unsigned bf16rne(float x) {
  unsigned u = __float_as_uint(x);
  return (u + 0x7fffu + ((u >> 16) & 1u)) >> 16;
}

// Reduce 32 9-term partials + 3x3 Jacobi eigh -> st[12] = {mu, Wm}.
// Called by ONE thread; deterministic (fixed order).
__device__ void zca_fin_dev(const float* __restrict__ part, float* st) {
  float tot[9];
#pragma unroll
  for (int k = 0; k < 9; k++) tot[k] = 0.f;
  for (int p = 0; p < 32; p++)
#pragma unroll
    for (int k = 0; k < 9; k++) tot[k] += part[p * 9 + k];
  const float M = (float)(CC * NN);
  float mu0 = tot[0] / M, mu1 = tot[1] / M, mu2 = tot[2] / M;
  float A[3][3];
  A[0][0] = (tot[3] - M * mu0 * mu0) / M + 1e-5f;
  A[0][1] = A[1][0] = (tot[4] - M * mu0 * mu1) / M;
  A[0][2] = A[2][0] = (tot[5] - M * mu0 * mu2) / M;
  A[1][1] = (tot[6] - M * mu1 * mu1) / M + 1e-5f;
  A[1][2] = A[2][1] = (tot[7] - M * mu1 * mu2) / M;
  A[2][2] = (tot[8] - M * mu2 * mu2) / M + 1e-5f;
  float V[3][3] = {{1.f, 0.f, 0.f}, {0.f, 1.f, 0.f}, {0.f, 0.f, 1.f}};
  for (int sweep = 0; sweep < 10; sweep++) {
    for (int pi = 0; pi < 3; pi++) {
      const int p = (pi == 2) ? 1 : 0;
      const int q = (pi == 0) ? 1 : 2;
      float apq = A[p][q];
      if (fabsf(apq) < 1e-30f) continue;
      float theta = (A[q][q] - A[p][p]) / (2.f * apq);
      float tt = 1.f / (fabsf(theta) + sqrtf(theta * theta + 1.f));
      if (theta < 0.f) tt = -tt;
      float cr = 1.f / sqrtf(tt * tt + 1.f);
      float sr = tt * cr;
      float app = A[p][p], aqq = A[q][q];
      A[p][p] = app - tt * apq;
      A[q][q] = aqq + tt * apq;
      A[p][q] = A[q][p] = 0.f;
      const int r = 3 - p - q;
      float arp = A[r][p], arq = A[r][q];
      A[r][p] = A[p][r] = cr * arp - sr * arq;
      A[r][q] = A[q][r] = sr * arp + cr * arq;
      for (int rr = 0; rr < 3; rr++) {
        float vrp = V[rr][p], vrq = V[rr][q];
        V[rr][p] = cr * vrp - sr * vrq;
        V[rr][q] = sr * vrp + cr * vrq;
      }
    }
  }
  float rs[3];
#pragma unroll
  for (int k = 0; k < 3; k++) rs[k] = rsqrtf(fmaxf(A[k][k], 1e-5f));
  st[0] = mu0; st[1] = mu1; st[2] = mu2;
  for (int u = 0; u < 3; u++)
    for (int v = 0; v < 3; v++) {
      float acc = 0.f;
      for (int k = 0; k < 3; k++) acc += V[u][k] * rs[k] * V[v][k];
      st[3 + u * 3 + v] = acc;
    }
}

// ---------------------------------------------------------------------------
// K1: q,k,v = Wq/Wk/Wv @ x in three layouts (r3 row-gather structure).
// grid (48 col-tiles of 16, 3 which, B), 256 threads
// ---------------------------------------------------------------------------
__global__ __launch_bounds__(256) void k_qkv(
    const float* __restrict__ x, const float* __restrict__ Wq,
    const float* __restrict__ Wk, const float* __restrict__ Wv,
    float* __restrict__ q_t, float* __restrict__ k_nat, float* __restrict__ v_t3)
{
  const int ct = blockIdx.x, which = blockIdx.y, b = blockIdx.z;
  const int col0 = ct * 16;
  __shared__ float xt[CC][16];
  const float* xb = x + (size_t)b * CC * COLS;
  for (int idx = threadIdx.x; idx < CC * 16; idx += 256) {
    int r = idx >> 4, cc = idx & 15;
    xt[r][cc] = xb[r * COLS + col0 + cc];
  }
  __syncthreads();
  const float* W = (which == 0) ? Wq : ((which == 1) ? Wk : Wv);
  const int co = threadIdx.x >> 1;
  const int cc0 = (threadIdx.x & 1) * 8;
  float acc[8];
#pragma unroll
  for (int k = 0; k < 8; k++) acc[k] = 0.f;
  const float* wrow = W + co * CC;
  for (int ci = 0; ci < CC; ci++) {
    float wv = wrow[ci];
#pragma unroll
    for (int k = 0; k < 8; k++) acc[k] = fmaf(wv, xt[ci][cc0 + k], acc[k]);
  }
#pragma unroll
  for (int k = 0; k < 8; k++) {
    int col = col0 + cc0 + k;
    int v = col >> 8, n = col & 255;
    float val = acc[k];
    if (which == 0)      q_t[((size_t)(b * NN + n) * CC + co) * 3 + v] = val;
    else if (which == 1) k_nat[(size_t)(b * CC + co) * COLS + col] = val;
    else                 v_t3[((size_t)(b * NN + n) * CC + co) * 3 + v] = val;
  }
}

// ---------------------------------------------------------------------------
// K1b: rel norms, WIDE: grid (N, B) x 1024 thr = full-chip occupancy.
// Thread (j = t&255, cq = t>>8) does 32 channels; LDS merge (fixed order).
// ---------------------------------------------------------------------------
__global__ __launch_bounds__(1024) void k_rel_w(
    const float* __restrict__ q_t, const float* __restrict__ k_nat,
    const float* __restrict__ pos, float* __restrict__ rm_all,
    float* __restrict__ rp_all)
{
  const int i = blockIdx.x, b = blockIdx.y;
  const int t = threadIdx.x;
  const int j = t & 255, cq = t >> 8;      // cq in 0..3
  __shared__ float qv[CC * 3];
  __shared__ float red[3][NN];
  for (int idx = t; idx < CC * 3; idx += 1024)
    qv[idx] = q_t[(size_t)(b * NN + i) * CC * 3 + idx];
  __syncthreads();
  const float* kb = k_nat + (size_t)b * CC * COLS + j;
  const int c0 = cq * 32;
  float s0 = 0.f, s1 = 0.f;
  for (int c = c0; c < c0 + 32; c += 2) {
    float kx0 = kb[c * COLS], ky0 = kb[c * COLS + 256], kz0 = kb[c * COLS + 512];
    float kx1 = kb[(c + 1) * COLS], ky1 = kb[(c + 1) * COLS + 256], kz1 = kb[(c + 1) * COLS + 512];
    float dx0 = kx0 - qv[c * 3], dy0 = ky0 - qv[c * 3 + 1], dz0 = kz0 - qv[c * 3 + 2];
    float dx1 = kx1 - qv[c * 3 + 3], dy1 = ky1 - qv[c * 3 + 4], dz1 = kz1 - qv[c * 3 + 5];
    float sq0 = dx0 * dx0 + dy0 * dy0 + dz0 * dz0;
    float sq1 = dx1 * dx1 + dy1 * dy1 + dz1 * dz1;
    s0 += (sq0 > 0.f) ? sqrtf(sq0) : 0.f;
    s1 += (sq1 > 0.f) ? sqrtf(sq1) : 0.f;
  }
  float s = s0 + s1;
  if (cq != 0) red[cq - 1][j] = s;
  __syncthreads();
  if (cq == 0) {
    float tot = ((s + red[0][j]) + (red[1][j] + red[2][j]));
    rm_all[(size_t)(b * NN + i) * NN + j] = tot * (1.f / 128.f);
    float dx = pos[(b * NN + i) * 3 + 0] - pos[(b * NN + j) * 3 + 0];
    float dy = pos[(b * NN + i) * 3 + 1] - pos[(b * NN + j) * 3 + 1];
    float dz = pos[(b * NN + i) * 3 + 2] - pos[(b * NN + j) * 3 + 2];
    float sq = dx * dx + dy * dy + dz * dz;
    rp_all[(size_t)(b * NN + i) * NN + j] = (sq > 0.f) ? sqrtf(sq) : 0.f;
  }
}

// ---------------------------------------------------------------------------
// K2: fused attention per (b, i, c-half). grid (N, 2, B), 256 threads.
// (r7/r11-proven version, unchanged)
// ---------------------------------------------------------------------------
__global__ __launch_bounds__(256, 4) void k_attn(
    const float* __restrict__ rm_all, const float* __restrict__ rp_all,
    const float* __restrict__ v_t3, const float* __restrict__ W1,
    const float* __restrict__ b1, const float* __restrict__ W2,
    float* __restrict__ a_nat)
{
  const int i = blockIdx.x, chalf = blockIdx.y, b = blockIdx.z;
  const int t = threadIdx.x;
  __shared__ __align__(16) short hh_s[64 * 64];
  __shared__ __align__(16) short w2_s[64 * 64];
  __shared__ float sc_s[64 * 65];
  __shared__ float rm_s[NN], rp_s[NN];

  rm_s[t] = rm_all[(size_t)(b * NN + i) * NN + t];
  rp_s[t] = rp_all[(size_t)(b * NN + i) * NN + t];
  {
    const int cl = t >> 2, h0 = (t & 3) * 16;
    const float* wrow = W2 + (size_t)(chalf * 64 + cl) * HH + h0;
#pragma unroll
    for (int e = 0; e < 8; e++) {
      unsigned lo = bf16rne(wrow[2 * e]);
      unsigned hi = bf16rne(wrow[2 * e + 1]);
      int didx = (cl * 32 + (h0 >> 1) + e) ^ ((cl & 7) << 2);
      ((unsigned*)w2_s)[didx] = lo | (hi << 16);
    }
  }
  const int h2 = (t & 31) * 2, jgrp = t >> 5;
  const float4 w1v = *reinterpret_cast<const float4*>(W1 + 2 * h2);
  const float c0 = b1[h2], c1 = b1[h2 + 1];
  __syncthreads();

  auto phase2 = [&](int q) {
#pragma unroll
    for (int jj = 0; jj < 8; jj++) {
      int jl = jgrp * 8 + jj;
      int jg = q * 64 + jl;
      float rmv = rm_s[jg], rpv = rp_s[jg];
      float g0 = fmaf(w1v.x, rmv, fmaf(w1v.y, rpv, c0));
      float g1 = fmaf(w1v.z, rmv, fmaf(w1v.w, rpv, c1));
      g0 = (g0 >= 0.f) ? g0 : NEG_ATTN * g0;
      g1 = (g1 >= 0.f) ? g1 : NEG_ATTN * g1;
      int didx = (jl * 32 + (h2 >> 1)) ^ ((jl & 7) << 2);
      ((unsigned*)hh_s)[didx] = bf16rne(g0) | (bf16rne(g1) << 16);
    }
  };

  phase2(0);
  __syncthreads();

  const int lane = t & 63, wv = t >> 6;
  const int g8 = (lane >> 4) * 8;
  const int cdx = wv * 16 + (lane & 15);
  const short8b bfr0 = *reinterpret_cast<const short8b*>(&w2_s[(cdx * 64 + g8) ^ ((cdx & 7) << 3)]);
  const short8b bfr1 = *reinterpret_cast<const short8b*>(&w2_s[(cdx * 64 + 32 + g8) ^ ((cdx & 7) << 3)]);

  const int cl = lane;
  const int par = wv;
  const int vc = chalf * 64 + cl;
  float l = 0.f, a0 = 0.f, a1 = 0.f, a2 = 0.f;

  for (int q = 0; q < 4; q++) {
#pragma unroll
    for (int jt = 0; jt < 4; jt++) {
      int jr = jt * 16 + (lane & 15);
      short8b af0 = *reinterpret_cast<const short8b*>(&hh_s[(jr * 64 + g8) ^ ((jr & 7) << 3)]);
      short8b af1 = *reinterpret_cast<const short8b*>(&hh_s[(jr * 64 + 32 + g8) ^ ((jr & 7) << 3)]);
      f32x4 acc = {0.f, 0.f, 0.f, 0.f};
      acc = __builtin_amdgcn_mfma_f32_16x16x32_bf16(af0, bfr0, acc, 0, 0, 0);
      acc = __builtin_amdgcn_mfma_f32_16x16x32_bf16(af1, bfr1, acc, 0, 0, 0);
      int row0 = jt * 16 + (lane >> 4) * 4;
      int ccol = wv * 16 + (lane & 15);
#pragma unroll
      for (int r = 0; r < 4; r++) sc_s[(row0 + r) * 65 + ccol] = acc[r];
    }
    __syncthreads();
#pragma unroll 4
    for (int jj = 0; jj < 16; jj++) {
      int jl = jj * 4 + par;
      int jg = q * 64 + jl;
      float s = sc_s[jl * 65 + cl];
      const float* vb = v_t3 + ((size_t)(b * NN + jg) * CC + vc) * 3;
      float v0 = vb[0], v1 = vb[1], v2 = vb[2];
      float p = __expf(s);
      l += p;
      a0 = fmaf(p, v0, a0);
      a1 = fmaf(p, v1, a1);
      a2 = fmaf(p, v2, a2);
    }
    if (q < 3) phase2(q + 1);
    __syncthreads();
  }

  float* mrg = sc_s;
  if (par != 0) {
    float* mp = mrg + (cl * 3 + (par - 1)) * 4;
    mp[0] = l; mp[1] = a0; mp[2] = a1; mp[3] = a2;
  }
  __syncthreads();
  if (par == 0) {
    float L = l, A0 = a0, A1 = a1, A2 = a2;
#pragma unroll
    for (int q = 0; q < 3; q++) {
      const float* mp = mrg + (cl * 3 + q) * 4;
      L += mp[0]; A0 += mp[1]; A1 += mp[2]; A2 += mp[3];
    }
    float inv = 1.f / L;
    float* ap = a_nat + (size_t)(b * CC + vc) * COLS + i;
    ap[0] = A0 * inv; ap[256] = A1 * inv; ap[512] = A2 * inv;
  }
}

// ---------------------------------------------------------------------------
// K3: y1 = x + Wo @ a_nat, nt-tiled (block sees all 3 v-comps); emits
// per-block ZCA partials from register values. grid (16, 2, B), 256 thr.
// (r14-proven)
// ---------------------------------------------------------------------------
__global__ __launch_bounds__(256) void k_wo_res_p(
    const float* __restrict__ a_nat, const float* __restrict__ Wo,
    const float* __restrict__ x, float* __restrict__ y1,
    float* __restrict__ part)
{
  const int nt = blockIdx.x, cohalf = blockIdx.y, b = blockIdx.z;
  const int n0 = nt * 16;
  const int t = threadIdx.x;
  __shared__ float at[CC][48];   // 24 KB
  const float* ab = a_nat + (size_t)b * CC * COLS;
  for (int idx = t; idx < CC * 16; idx += 256) {
    int ci = idx >> 4, nn = idx & 15;
    const float* row = ab + ci * COLS + n0 + nn;
    at[ci][nn]      = row[0];
    at[ci][16 + nn] = row[256];
    at[ci][32 + nn] = row[512];
  }
  __syncthreads();
  const int co = cohalf * 64 + (t >> 2);
  const int nn0 = (t & 3) * 4;
  float acc[3][4];
#pragma unroll
  for (int v = 0; v < 3; v++)
#pragma unroll
    for (int k = 0; k < 4; k++) acc[v][k] = 0.f;
  const float* wrow = Wo + co * CC;
  for (int ci = 0; ci < CC; ci++) {
    float wv = wrow[ci];
#pragma unroll
    for (int v = 0; v < 3; v++)
#pragma unroll
      for (int k = 0; k < 4; k++)
        acc[v][k] = fmaf(wv, at[ci][v * 16 + nn0 + k], acc[v][k]);
  }
  float v9[9];
#pragma unroll
  for (int k = 0; k < 9; k++) v9[k] = 0.f;
  const size_t base = (size_t)(b * CC + co) * COLS + n0 + nn0;
#pragma unroll
  for (int k = 0; k < 4; k++) {
    float y0 = x[base + k]        + acc[0][k];
    float y1v = x[base + 256 + k] + acc[1][k];
    float y2 = x[base + 512 + k]  + acc[2][k];
    y1[base + k]       = y0;
    y1[base + 256 + k] = y1v;
    y1[base + 512 + k] = y2;
    v9[0] += y0; v9[1] += y1v; v9[2] += y2;
    v9[3] += y0 * y0; v9[4] += y0 * y1v; v9[5] += y0 * y2;
    v9[6] += y1v * y1v; v9[7] += y1v * y2; v9[8] += y2 * y2;
  }
#pragma unroll
  for (int off = 32; off >= 1; off >>= 1)
#pragma unroll
    for (int k = 0; k < 9; k++) v9[k] += __shfl_down(v9[k], off);
  __syncthreads();
  float* red = &at[0][0];
  const int wid = t >> 6, lane = t & 63;
  if (lane == 0)
#pragma unroll
    for (int k = 0; k < 9; k++) red[wid * 9 + k] = v9[k];
  __syncthreads();
  if (t == 0)
#pragma unroll
    for (int k = 0; k < 9; k++)
      part[(size_t)(b * 32 + nt * 2 + cohalf) * 9 + k] =
          (red[k] + red[9 + k]) + (red[18 + k] + red[27 + k]);
}

// ---------------------------------------------------------------------------
// K6: FFN1, in-block ZCA finalize from part1, whitening fused on read.
// grid (16, 4, B), 256 thr.
// ---------------------------------------------------------------------------
__global__ __launch_bounds__(256) void k_ffn1_f(
    const float* __restrict__ y1, const float* __restrict__ part,
    const float* __restrict__ gamma, const float* __restrict__ Wfeat,
    const float* __restrict__ Wdir, float* __restrict__ hout)
{
  const int nt = blockIdx.x, cs = blockIdx.y, b = blockIdx.z;
  const int n0 = nt * 16, co0 = cs * 64;
  __shared__ float xt[CC][48];
  __shared__ float st[12];
  if (threadIdx.x == 0) zca_fin_dev(part + (size_t)b * 32 * 9, st);
  __syncthreads();
  const float* yb = y1 + (size_t)b * CC * COLS;
  for (int idx = threadIdx.x; idx < CC * 16; idx += 256) {
    int ci = idx >> 4, nn = idx & 15;
    const float* row = yb + ci * COLS + n0 + nn;
    float d0 = row[0] - st[0], d1 = row[256] - st[1], d2 = row[512] - st[2];
    float g = gamma[ci];
    xt[ci][nn]      = g * (st[3] * d0 + st[4] * d1 + st[5] * d2);
    xt[ci][16 + nn] = g * (st[6] * d0 + st[7] * d1 + st[8] * d2);
    xt[ci][32 + nn] = g * (st[9] * d0 + st[10] * d1 + st[11] * d2);
  }
  __syncthreads();
  const int co = co0 + (threadIdx.x & 63);
  const int nn0 = (threadIdx.x >> 6) * 4;
  float p[3][4], d[3][4];
#pragma unroll
  for (int v = 0; v < 3; v++)
#pragma unroll
    for (int k = 0; k < 4; k++) { p[v][k] = 0.f; d[v][k] = 0.f; }
  const float* wf = Wfeat + co * CC;
  const float* wd = Wdir + co * CC;
  for (int ci = 0; ci < CC; ci++) {
    float a = wf[ci], bb = wd[ci];
#pragma unroll
    for (int v = 0; v < 3; v++)
#pragma unroll
      for (int k = 0; k < 4; k++) {
        float xv = xt[ci][v * 16 + nn0 + k];
        p[v][k] = fmaf(a, xv, p[v][k]);
        d[v][k] = fmaf(bb, xv, d[v][k]);
      }
  }
  float* hb = hout + (size_t)(b * CHX + co) * COLS;
#pragma unroll
  for (int k = 0; k < 4; k++) {
    float dot = p[0][k] * d[0][k] + p[1][k] * d[1][k] + p[2][k] * d[2][k];
    float dsq = d[0][k] * d[0][k] + d[1][k] * d[1][k] + d[2][k] * d[2][k];
    float coef = (dot >= 0.f) ? 0.f : (1.f - NEG_FFN) * dot / (dsq + 1e-6f);
#pragma unroll
    for (int v = 0; v < 3; v++)
      hb[v * 256 + n0 + nn0 + k] = p[v][k] - coef * d[v][k];
  }
}

// ---------------------------------------------------------------------------
// K7: x2 = whiten(y1) + Wffn2 @ h, nt-tiled; in-block finalize from part1;
// emits per-block partials of x2. grid (16, 2, B), 256 thr. LDS 48 KB.
// (r14-proven body + in-block fin)
// ---------------------------------------------------------------------------
__global__ __launch_bounds__(256) void k_ffn2_pf(
    const float* __restrict__ h, const float* __restrict__ Wffn2,
    const float* __restrict__ y1, const float* __restrict__ part1,
    const float* __restrict__ gamma, float* __restrict__ x2,
    float* __restrict__ part2)
{
  const int nt = blockIdx.x, cohalf = blockIdx.y, b = blockIdx.z;
  const int n0 = nt * 16;
  const int t = threadIdx.x;
  __shared__ float ht[CHX][48];   // 48 KB
  __shared__ float st[12];
  if (t == 0) zca_fin_dev(part1 + (size_t)b * 32 * 9, st);
  const float* hb = h + (size_t)b * CHX * COLS;
  for (int idx = t; idx < CHX * 16; idx += 256) {
    int ci = idx >> 4, nn = idx & 15;
    const float* row = hb + ci * COLS + n0 + nn;
    ht[ci][nn]      = row[0];
    ht[ci][16 + nn] = row[256];
    ht[ci][32 + nn] = row[512];
  }
  __syncthreads();
  const int co = cohalf * 64 + (t >> 2);
  const int nn0 = (t & 3) * 4;
  float acc[3][4];
#pragma unroll
  for (int v = 0; v < 3; v++)
#pragma unroll
    for (int k = 0; k < 4; k++) acc[v][k] = 0.f;
  const float* w = Wffn2 + co * CHX;
  for (int ci = 0; ci < CHX; ci++) {
    float wv = w[ci];
#pragma unroll
    for (int v = 0; v < 3; v++)
#pragma unroll
      for (int k = 0; k < 4; k++)
        acc[v][k] = fmaf(wv, ht[ci][v * 16 + nn0 + k], acc[v][k]);
  }
  const float g = gamma[co];
  const float* yb = y1 + (size_t)(b * CC + co) * COLS + n0 + nn0;
  const size_t base = (size_t)(b * CC + co) * COLS + n0 + nn0;
  float v9[9];
#pragma unroll
  for (int k = 0; k < 9; k++) v9[k] = 0.f;
#pragma unroll
  for (int k = 0; k < 4; k++) {
    float d0 = yb[k] - st[0], d1 = yb[256 + k] - st[1], d2 = yb[512 + k] - st[2];
    float x0 = g * (st[3] * d0 + st[4] * d1 + st[5] * d2) + acc[0][k];
    float x1 = g * (st[6] * d0 + st[7] * d1 + st[8] * d2) + acc[1][k];
    float xz = g * (st[9] * d0 + st[10] * d1 + st[11] * d2) + acc[2][k];
    x2[base + k]       = x0;
    x2[base + 256 + k] = x1;
    x2[base + 512 + k] = xz;
    v9[0] += x0; v9[1] += x1; v9[2] += xz;
    v9[3] += x0 * x0; v9[4] += x0 * x1; v9[5] += x0 * xz;
    v9[6] += x1 * x1; v9[7] += x1 * xz; v9[8] += xz * xz;
  }
#pragma unroll
  for (int off = 32; off >= 1; off >>= 1)
#pragma unroll
    for (int k = 0; k < 9; k++) v9[k] += __shfl_down(v9[k], off);
  __syncthreads();
  float* red = &ht[0][0];
  const int wid = t >> 6, lane = t & 63;
  if (lane == 0)
#pragma unroll
    for (int k = 0; k < 9; k++) red[wid * 9 + k] = v9[k];
  __syncthreads();
  if (t == 0)
#pragma unroll
    for (int k = 0; k < 9; k++)
      part2[(size_t)(b * 32 + nt * 2 + cohalf) * 9 + k] =
          (red[k] + red[9 + k]) + (red[18 + k] + red[27 + k]);
}

// ---------------------------------------------------------------------------
// K8: final whitening apply with in-block finalize from part2 -> out.
// grid (256), 256 thr; b = blockIdx >> 7 (block-uniform).
// ---------------------------------------------------------------------------
__global__ __launch_bounds__(256) void k_zca_apply_f(
    const float* __restrict__ y, const float* __restrict__ part,
    const float* __restrict__ gamma, float* __restrict__ out)
{
  const int b = blockIdx.x >> 7;
  __shared__ float st[12];
  if (threadIdx.x == 0) zca_fin_dev(part + (size_t)b * 32 * 9, st);
  __syncthreads();
  int idx = blockIdx.x * blockDim.x + threadIdx.x;
  int rem = idx & 32767;
  int cidx = rem >> 8, n = rem & 255;
  const size_t base = (size_t)(b * CC + cidx) * COLS + n;
  float v0 = y[base] - st[0];
  float v1 = y[base + 256] - st[1];
  float v2 = y[base + 512] - st[2];
  float g = gamma[cidx];
  out[base]       = g * (st[3] * v0 + st[4] * v1 + st[5] * v2);
  out[base + 256] = g * (st[6] * v0 + st[7] * v1 + st[8] * v2);
  out[base + 512] = g * (st[9] * v0 + st[10] * v1 + st[11] * v2);
}

// ---------------------------------------------------------------------------
// Workspace: FULLY DISJOINT. QKV=196,608  RM=131,072  HB=393,216 floats.
// 7 launches: qkv, rel_w, attn, wo_res_p, ffn1_f, ffn2_pf, apply_f.
// ---------------------------------------------------------------------------
extern "C" void kernel_launch(void* const* d_in, const int* in_sizes, int n_in,
                              void* d_out, int out_size, void* d_ws, size_t ws_size,
                              hipStream_t stream)
{
  (void)in_sizes; (void)n_in; (void)out_size; (void)ws_size;
  const float* x      = (const float*)d_in[0];
  const float* pos    = (const float*)d_in[1];
  const float* Wq     = (const float*)d_in[2];
  const float* Wk     = (const float*)d_in[3];
  const float* Wv     = (const float*)d_in[4];
  const float* Wo     = (const float*)d_in[5];
  const float* W1     = (const float*)d_in[6];
  const float* b1     = (const float*)d_in[7];
  const float* W2     = (const float*)d_in[8];
  // d_in[9] = b2 : dropped (softmax shift-invariant per channel)
  const float* gamma1 = (const float*)d_in[10];
  const float* Wfeat  = (const float*)d_in[11];
  const float* Wdir   = (const float*)d_in[12];
  const float* Wffn2  = (const float*)d_in[13];
  const float* gamma2 = (const float*)d_in[14];

  float* ws = (float*)d_ws;
  const size_t QKV = (size_t)BB * NN * CC * 3;   // 196,608
  const size_t RM  = (size_t)BB * NN * NN;       // 131,072
  const size_t HB  = (size_t)BB * CHX * COLS;    // 393,216

  float* q_t    = ws;
  float* k_nat  = q_t    + QKV;
  float* v_t3   = k_nat  + QKV;
  float* rm_all = v_t3   + QKV;
  float* rp_all = rm_all + RM;
  float* a_nat  = rp_all + RM;
  float* y1     = a_nat  + QKV;
  float* hbuf   = y1     + QKV;
  float* x2     = hbuf   + HB;
  float* part1  = x2     + QKV;         // 2*32*9 = 576 floats
  float* part2  = part1  + 640;         // 576 floats

  k_qkv<<<dim3(48, 3, BB), 256, 0, stream>>>(x, Wq, Wk, Wv, q_t, k_nat, v_t3);
  k_rel_w<<<dim3(NN, BB), 1024, 0, stream>>>(q_t, k_nat, pos, rm_all, rp_all);
  k_attn<<<dim3(NN, 2, BB), 256, 0, stream>>>(rm_all, rp_all, v_t3, W1, b1, W2, a_nat);
  k_wo_res_p<<<dim3(16, 2, BB), 256, 0, stream>>>(a_nat, Wo, x, y1, part1);
  k_ffn1_f<<<dim3(16, 4, BB), 256, 0, stream>>>(y1, part1, gamma1, Wfeat, Wdir, hbuf);
  k_ffn2_pf<<<dim3(16, 2, BB), 256, 0, stream>>>(hbuf, Wffn2, y1, part1, gamma1, x2, part2);
  k_zca_apply_f<<<256, 256, 0, stream>>>(x2, part2, gamma2, (float*)d_out);
}

// Round 17
// 105.145 us; speedup vs baseline: 1.0054x; 1.0054x over previous
//
#include <hip/hip_runtime.h>
#include <math.h>

// Problem constants (B=2, C=128, N=256, H=64, CH=256)
#define BB 2
#define CC 128
#define NN 256
#define HH 64
#define CHX 256
#define COLS 768           // 3*N flattened (v,n) columns
#define NEG_ATTN 0.2f
#define NEG_FFN 0.1f

typedef __attribute__((ext_vector_type(8))) short short8b;   // 8 bf16 (4 VGPRs)
typedef __attribute__((ext_vector_type(4))) float f32x4;

__device__ __forceinline__ unsigned bf16rne(float x) {
  unsigned u = __float_as_uint(x);
  return (u + 0x7fffu + ((u >> 16) & 1u)) >> 16;
}

// ---------------------------------------------------------------------------
// K1: q,k,v = Wq/Wk/Wv @ x in three layouts (r3 row-gather structure).
// grid (48 col-tiles of 16, 3 which, B), 256 threads
// ---------------------------------------------------------------------------
__global__ __launch_bounds__(256) void k_qkv(
    const float* __restrict__ x, const float* __restrict__ Wq,
    const float* __restrict__ Wk, const float* __restrict__ Wv,
    float* __restrict__ q_t, float* __restrict__ k_nat, float* __restrict__ v_t3)
{
  const int ct = blockIdx.x, which = blockIdx.y, b = blockIdx.z;
  const int col0 = ct * 16;
  __shared__ float xt[CC][16];
  const float* xb = x + (size_t)b * CC * COLS;
  for (int idx = threadIdx.x; idx < CC * 16; idx += 256) {
    int r = idx >> 4, cc = idx & 15;
    xt[r][cc] = xb[r * COLS + col0 + cc];
  }
  __syncthreads();
  const float* W = (which == 0) ? Wq : ((which == 1) ? Wk : Wv);
  const int co = threadIdx.x >> 1;
  const int cc0 = (threadIdx.x & 1) * 8;
  float acc[8];
#pragma unroll
  for (int k = 0; k < 8; k++) acc[k] = 0.f;
  const float* wrow = W + co * CC;
  for (int ci = 0; ci < CC; ci++) {
    float wv = wrow[ci];
#pragma unroll
    for (int k = 0; k < 8; k++) acc[k] = fmaf(wv, xt[ci][cc0 + k], acc[k]);
  }
#pragma unroll
  for (int k = 0; k < 8; k++) {
    int col = col0 + cc0 + k;
    int v = col >> 8, n = col & 255;
    float val = acc[k];
    if (which == 0)      q_t[((size_t)(b * NN + n) * CC + co) * 3 + v] = val;
    else if (which == 1) k_nat[(size_t)(b * CC + co) * COLS + col] = val;
    else                 v_t3[((size_t)(b * NN + n) * CC + co) * 3 + v] = val;
  }
}

// ---------------------------------------------------------------------------
// K1b: rel norms, WIDE: grid (N, B) x 1024 thr = full-chip occupancy.
// Thread (j = t&255, cq = t>>8) does 32 channels; LDS merge (fixed order).
// (r15-proven)
// ---------------------------------------------------------------------------
__global__ __launch_bounds__(1024) void k_rel_w(
    const float* __restrict__ q_t, const float* __restrict__ k_nat,
    const float* __restrict__ pos, float* __restrict__ rm_all,
    float* __restrict__ rp_all)
{
  const int i = blockIdx.x, b = blockIdx.y;
  const int t = threadIdx.x;
  const int j = t & 255, cq = t >> 8;      // cq in 0..3
  __shared__ float qv[CC * 3];
  __shared__ float red[3][NN];
  for (int idx = t; idx < CC * 3; idx += 1024)
    qv[idx] = q_t[(size_t)(b * NN + i) * CC * 3 + idx];
  __syncthreads();
  const float* kb = k_nat + (size_t)b * CC * COLS + j;
  const int c0 = cq * 32;
  float s0 = 0.f, s1 = 0.f;
  for (int c = c0; c < c0 + 32; c += 2) {
    float kx0 = kb[c * COLS], ky0 = kb[c * COLS + 256], kz0 = kb[c * COLS + 512];
    float kx1 = kb[(c + 1) * COLS], ky1 = kb[(c + 1) * COLS + 256], kz1 = kb[(c + 1) * COLS + 512];
    float dx0 = kx0 - qv[c * 3], dy0 = ky0 - qv[c * 3 + 1], dz0 = kz0 - qv[c * 3 + 2];
    float dx1 = kx1 - qv[c * 3 + 3], dy1 = ky1 - qv[c * 3 + 4], dz1 = kz1 - qv[c * 3 + 5];
    float sq0 = dx0 * dx0 + dy0 * dy0 + dz0 * dz0;
    float sq1 = dx1 * dx1 + dy1 * dy1 + dz1 * dz1;
    s0 += (sq0 > 0.f) ? sqrtf(sq0) : 0.f;
    s1 += (sq1 > 0.f) ? sqrtf(sq1) : 0.f;
  }
  float s = s0 + s1;
  if (cq != 0) red[cq - 1][j] = s;
  __syncthreads();
  if (cq == 0) {
    float tot = ((s + red[0][j]) + (red[1][j] + red[2][j]));
    rm_all[(size_t)(b * NN + i) * NN + j] = tot * (1.f / 128.f);
    float dx = pos[(b * NN + i) * 3 + 0] - pos[(b * NN + j) * 3 + 0];
    float dy = pos[(b * NN + i) * 3 + 1] - pos[(b * NN + j) * 3 + 1];
    float dz = pos[(b * NN + i) * 3 + 2] - pos[(b * NN + j) * 3 + 2];
    float sq = dx * dx + dy * dy + dz * dz;
    rp_all[(size_t)(b * NN + i) * NN + j] = (sq > 0.f) ? sqrtf(sq) : 0.f;
  }
}

// ---------------------------------------------------------------------------
// K2: fused attention per (b, i, c-half). grid (N, 2, B), 256 threads.
// (r7/r11-proven version, unchanged)
// ---------------------------------------------------------------------------
__global__ __launch_bounds__(256, 4) void k_attn(
    const float* __restrict__ rm_all, const float* __restrict__ rp_all,
    const float* __restrict__ v_t3, const float* __restrict__ W1,
    const float* __restrict__ b1, const float* __restrict__ W2,
    float* __restrict__ a_nat)
{
  const int i = blockIdx.x, chalf = blockIdx.y, b = blockIdx.z;
  const int t = threadIdx.x;
  __shared__ __align__(16) short hh_s[64 * 64];
  __shared__ __align__(16) short w2_s[64 * 64];
  __shared__ float sc_s[64 * 65];
  __shared__ float rm_s[NN], rp_s[NN];

  rm_s[t] = rm_all[(size_t)(b * NN + i) * NN + t];
  rp_s[t] = rp_all[(size_t)(b * NN + i) * NN + t];
  {
    const int cl = t >> 2, h0 = (t & 3) * 16;
    const float* wrow = W2 + (size_t)(chalf * 64 + cl) * HH + h0;
#pragma unroll
    for (int e = 0; e < 8; e++) {
      unsigned lo = bf16rne(wrow[2 * e]);
      unsigned hi = bf16rne(wrow[2 * e + 1]);
      int didx = (cl * 32 + (h0 >> 1) + e) ^ ((cl & 7) << 2);
      ((unsigned*)w2_s)[didx] = lo | (hi << 16);
    }
  }
  const int h2 = (t & 31) * 2, jgrp = t >> 5;
  const float4 w1v = *reinterpret_cast<const float4*>(W1 + 2 * h2);
  const float c0 = b1[h2], c1 = b1[h2 + 1];
  __syncthreads();

  auto phase2 = [&](int q) {
#pragma unroll
    for (int jj = 0; jj < 8; jj++) {
      int jl = jgrp * 8 + jj;
      int jg = q * 64 + jl;
      float rmv = rm_s[jg], rpv = rp_s[jg];
      float g0 = fmaf(w1v.x, rmv, fmaf(w1v.y, rpv, c0));
      float g1 = fmaf(w1v.z, rmv, fmaf(w1v.w, rpv, c1));
      g0 = (g0 >= 0.f) ? g0 : NEG_ATTN * g0;
      g1 = (g1 >= 0.f) ? g1 : NEG_ATTN * g1;
      int didx = (jl * 32 + (h2 >> 1)) ^ ((jl & 7) << 2);
      ((unsigned*)hh_s)[didx] = bf16rne(g0) | (bf16rne(g1) << 16);
    }
  };

  phase2(0);
  __syncthreads();

  const int lane = t & 63, wv = t >> 6;
  const int g8 = (lane >> 4) * 8;
  const int cdx = wv * 16 + (lane & 15);
  const short8b bfr0 = *reinterpret_cast<const short8b*>(&w2_s[(cdx * 64 + g8) ^ ((cdx & 7) << 3)]);
  const short8b bfr1 = *reinterpret_cast<const short8b*>(&w2_s[(cdx * 64 + 32 + g8) ^ ((cdx & 7) << 3)]);

  const int cl = lane;
  const int par = wv;
  const int vc = chalf * 64 + cl;
  float l = 0.f, a0 = 0.f, a1 = 0.f, a2 = 0.f;

  for (int q = 0; q < 4; q++) {
#pragma unroll
    for (int jt = 0; jt < 4; jt++) {
      int jr = jt * 16 + (lane & 15);
      short8b af0 = *reinterpret_cast<const short8b*>(&hh_s[(jr * 64 + g8) ^ ((jr & 7) << 3)]);
      short8b af1 = *reinterpret_cast<const short8b*>(&hh_s[(jr * 64 + 32 + g8) ^ ((jr & 7) << 3)]);
      f32x4 acc = {0.f, 0.f, 0.f, 0.f};
      acc = __builtin_amdgcn_mfma_f32_16x16x32_bf16(af0, bfr0, acc, 0, 0, 0);
      acc = __builtin_amdgcn_mfma_f32_16x16x32_bf16(af1, bfr1, acc, 0, 0, 0);
      int row0 = jt * 16 + (lane >> 4) * 4;
      int ccol = wv * 16 + (lane & 15);
#pragma unroll
      for (int r = 0; r < 4; r++) sc_s[(row0 + r) * 65 + ccol] = acc[r];
    }
    __syncthreads();
#pragma unroll 4
    for (int jj = 0; jj < 16; jj++) {
      int jl = jj * 4 + par;
      int jg = q * 64 + jl;
      float s = sc_s[jl * 65 + cl];
      const float* vb = v_t3 + ((size_t)(b * NN + jg) * CC + vc) * 3;
      float v0 = vb[0], v1 = vb[1], v2 = vb[2];
      float p = __expf(s);
      l += p;
      a0 = fmaf(p, v0, a0);
      a1 = fmaf(p, v1, a1);
      a2 = fmaf(p, v2, a2);
    }
    if (q < 3) phase2(q + 1);
    __syncthreads();
  }

  float* mrg = sc_s;
  if (par != 0) {
    float* mp = mrg + (cl * 3 + (par - 1)) * 4;
    mp[0] = l; mp[1] = a0; mp[2] = a1; mp[3] = a2;
  }
  __syncthreads();
  if (par == 0) {
    float L = l, A0 = a0, A1 = a1, A2 = a2;
#pragma unroll
    for (int q = 0; q < 3; q++) {
      const float* mp = mrg + (cl * 3 + q) * 4;
      L += mp[0]; A0 += mp[1]; A1 += mp[2]; A2 += mp[3];
    }
    float inv = 1.f / L;
    float* ap = a_nat + (size_t)(b * CC + vc) * COLS + i;
    ap[0] = A0 * inv; ap[256] = A1 * inv; ap[512] = A2 * inv;
  }
}

// ---------------------------------------------------------------------------
// K3: y1 = x + Wo @ a_nat, nt-tiled (block sees all 3 v-comps); emits
// per-block ZCA partials from register values. grid (16, 2, B), 256 thr.
// (r14-proven)
// ---------------------------------------------------------------------------
__global__ __launch_bounds__(256) void k_wo_res_p(
    const float* __restrict__ a_nat, const float* __restrict__ Wo,
    const float* __restrict__ x, float* __restrict__ y1,
    float* __restrict__ part)
{
  const int nt = blockIdx.x, cohalf = blockIdx.y, b = blockIdx.z;
  const int n0 = nt * 16;
  const int t = threadIdx.x;
  __shared__ float at[CC][48];   // 24 KB
  const float* ab = a_nat + (size_t)b * CC * COLS;
  for (int idx = t; idx < CC * 16; idx += 256) {
    int ci = idx >> 4, nn = idx & 15;
    const float* row = ab + ci * COLS + n0 + nn;
    at[ci][nn]      = row[0];
    at[ci][16 + nn] = row[256];
    at[ci][32 + nn] = row[512];
  }
  __syncthreads();
  const int co = cohalf * 64 + (t >> 2);
  const int nn0 = (t & 3) * 4;
  float acc[3][4];
#pragma unroll
  for (int v = 0; v < 3; v++)
#pragma unroll
    for (int k = 0; k < 4; k++) acc[v][k] = 0.f;
  const float* wrow = Wo + co * CC;
  for (int ci = 0; ci < CC; ci++) {
    float wv = wrow[ci];
#pragma unroll
    for (int v = 0; v < 3; v++)
#pragma unroll
      for (int k = 0; k < 4; k++)
        acc[v][k] = fmaf(wv, at[ci][v * 16 + nn0 + k], acc[v][k]);
  }
  float v9[9];
#pragma unroll
  for (int k = 0; k < 9; k++) v9[k] = 0.f;
  const size_t base = (size_t)(b * CC + co) * COLS + n0 + nn0;
#pragma unroll
  for (int k = 0; k < 4; k++) {
    float y0 = x[base + k]        + acc[0][k];
    float y1v = x[base + 256 + k] + acc[1][k];
    float y2 = x[base + 512 + k]  + acc[2][k];
    y1[base + k]       = y0;
    y1[base + 256 + k] = y1v;
    y1[base + 512 + k] = y2;
    v9[0] += y0; v9[1] += y1v; v9[2] += y2;
    v9[3] += y0 * y0; v9[4] += y0 * y1v; v9[5] += y0 * y2;
    v9[6] += y1v * y1v; v9[7] += y1v * y2; v9[8] += y2 * y2;
  }
#pragma unroll
  for (int off = 32; off >= 1; off >>= 1)
#pragma unroll
    for (int k = 0; k < 9; k++) v9[k] += __shfl_down(v9[k], off);
  __syncthreads();
  float* red = &at[0][0];
  const int wid = t >> 6, lane = t & 63;
  if (lane == 0)
#pragma unroll
    for (int k = 0; k < 9; k++) red[wid * 9 + k] = v9[k];
  __syncthreads();
  if (t == 0)
#pragma unroll
    for (int k = 0; k < 9; k++)
      part[(size_t)(b * 32 + nt * 2 + cohalf) * 9 + k] =
          (red[k] + red[9 + k]) + (red[18 + k] + red[27 + k]);
}

// ---------------------------------------------------------------------------
// K5: finalize ZCA from 32 partials: reduce + 3x3 Jacobi -> mu + Wm.
// grid (B), 64 thr (thread 0 only; deterministic). (r14-proven)
// ---------------------------------------------------------------------------
__global__ __launch_bounds__(64) void k_zca_fin(
    const float* __restrict__ partials, float* __restrict__ stats)
{
  const int b = blockIdx.x;
  if (threadIdx.x != 0) return;
  float tot[9];
#pragma unroll
  for (int k = 0; k < 9; k++) tot[k] = 0.f;
  for (int p = 0; p < 32; p++)
#pragma unroll
    for (int k = 0; k < 9; k++) tot[k] += partials[(size_t)(b * 32 + p) * 9 + k];
  const float M = (float)(CC * NN);
  float mu0 = tot[0] / M, mu1 = tot[1] / M, mu2 = tot[2] / M;
  float A[3][3];
  A[0][0] = (tot[3] - M * mu0 * mu0) / M + 1e-5f;
  A[0][1] = A[1][0] = (tot[4] - M * mu0 * mu1) / M;
  A[0][2] = A[2][0] = (tot[5] - M * mu0 * mu2) / M;
  A[1][1] = (tot[6] - M * mu1 * mu1) / M + 1e-5f;
  A[1][2] = A[2][1] = (tot[7] - M * mu1 * mu2) / M;
  A[2][2] = (tot[8] - M * mu2 * mu2) / M + 1e-5f;
  float V[3][3] = {{1.f, 0.f, 0.f}, {0.f, 1.f, 0.f}, {0.f, 0.f, 1.f}};
  for (int sweep = 0; sweep < 10; sweep++) {
    for (int pi = 0; pi < 3; pi++) {
      const int p = (pi == 2) ? 1 : 0;
      const int q = (pi == 0) ? 1 : 2;
      float apq = A[p][q];
      if (fabsf(apq) < 1e-30f) continue;
      float theta = (A[q][q] - A[p][p]) / (2.f * apq);
      float tt = 1.f / (fabsf(theta) + sqrtf(theta * theta + 1.f));
      if (theta < 0.f) tt = -tt;
      float cr = 1.f / sqrtf(tt * tt + 1.f);
      float sr = tt * cr;
      float app = A[p][p], aqq = A[q][q];
      A[p][p] = app - tt * apq;
      A[q][q] = aqq + tt * apq;
      A[p][q] = A[q][p] = 0.f;
      const int r = 3 - p - q;
      float arp = A[r][p], arq = A[r][q];
      A[r][p] = A[p][r] = cr * arp - sr * arq;
      A[r][q] = A[q][r] = sr * arp + cr * arq;
      for (int rr = 0; rr < 3; rr++) {
        float vrp = V[rr][p], vrq = V[rr][q];
        V[rr][p] = cr * vrp - sr * vrq;
        V[rr][q] = sr * vrp + cr * vrq;
      }
    }
  }
  float rs[3];
#pragma unroll
  for (int k = 0; k < 3; k++) rs[k] = rsqrtf(fmaxf(A[k][k], 1e-5f));
  float* st = stats + b * 12;
  st[0] = mu0; st[1] = mu1; st[2] = mu2;
  for (int u = 0; u < 3; u++)
    for (int v = 0; v < 3; v++) {
      float acc = 0.f;
      for (int k = 0; k < 3; k++) acc += V[u][k] * rs[k] * V[v][k];
      st[3 + u * 3 + v] = acc;
    }
}

// ---------------------------------------------------------------------------
// K6: FFN1 with fused whitening on read. grid (16, 4, B), 256 thr. (r11)
// ---------------------------------------------------------------------------
__global__ __launch_bounds__(256) void k_ffn1(
    const float* __restrict__ y1, const float* __restrict__ stats,
    const float* __restrict__ gamma, const float* __restrict__ Wfeat,
    const float* __restrict__ Wdir, float* __restrict__ hout)
{
  const int nt = blockIdx.x, cs = blockIdx.y, b = blockIdx.z;
  const int n0 = nt * 16, co0 = cs * 64;
  __shared__ float xt[CC][48];
  const float* yb = y1 + (size_t)b * CC * COLS;
  const float* st = stats + b * 12;
  for (int idx = threadIdx.x; idx < CC * 16; idx += 256) {
    int ci = idx >> 4, nn = idx & 15;
    const float* row = yb + ci * COLS + n0 + nn;
    float d0 = row[0] - st[0], d1 = row[256] - st[1], d2 = row[512] - st[2];
    float g = gamma[ci];
    xt[ci][nn]      = g * (st[3] * d0 + st[4] * d1 + st[5] * d2);
    xt[ci][16 + nn] = g * (st[6] * d0 + st[7] * d1 + st[8] * d2);
    xt[ci][32 + nn] = g * (st[9] * d0 + st[10] * d1 + st[11] * d2);
  }
  __syncthreads();
  const int co = co0 + (threadIdx.x & 63);
  const int nn0 = (threadIdx.x >> 6) * 4;
  float p[3][4], d[3][4];
#pragma unroll
  for (int v = 0; v < 3; v++)
#pragma unroll
    for (int k = 0; k < 4; k++) { p[v][k] = 0.f; d[v][k] = 0.f; }
  const float* wf = Wfeat + co * CC;
  const float* wd = Wdir + co * CC;
  for (int ci = 0; ci < CC; ci++) {
    float a = wf[ci], bb = wd[ci];
#pragma unroll
    for (int v = 0; v < 3; v++)
#pragma unroll
      for (int k = 0; k < 4; k++) {
        float xv = xt[ci][v * 16 + nn0 + k];
        p[v][k] = fmaf(a, xv, p[v][k]);
        d[v][k] = fmaf(bb, xv, d[v][k]);
      }
  }
  float* hb = hout + (size_t)(b * CHX + co) * COLS;
#pragma unroll
  for (int k = 0; k < 4; k++) {
    float dot = p[0][k] * d[0][k] + p[1][k] * d[1][k] + p[2][k] * d[2][k];
    float dsq = d[0][k] * d[0][k] + d[1][k] * d[1][k] + d[2][k] * d[2][k];
    float coef = (dot >= 0.f) ? 0.f : (1.f - NEG_FFN) * dot / (dsq + 1e-6f);
#pragma unroll
    for (int v = 0; v < 3; v++)
      hb[v * 256 + n0 + nn0 + k] = p[v][k] - coef * d[v][k];
  }
}

// ---------------------------------------------------------------------------
// K7: x2 = whiten(y1) + Wffn2 @ h, nt-tiled; emits per-block ZCA partials.
// grid (16 nt, 2 cohalf, B), 256 thr. LDS 48 KB. (r14-proven)
// ---------------------------------------------------------------------------
__global__ __launch_bounds__(256) void k_ffn2_p(
    const float* __restrict__ h, const float* __restrict__ Wffn2,
    const float* __restrict__ y1, const float* __restrict__ stats,
    const float* __restrict__ gamma, float* __restrict__ x2,
    float* __restrict__ part)
{
  const int nt = blockIdx.x, cohalf = blockIdx.y, b = blockIdx.z;
  const int n0 = nt * 16;
  const int t = threadIdx.x;
  __shared__ float ht[CHX][48];   // 48 KB
  const float* hb = h + (size_t)b * CHX * COLS;
  for (int idx = t; idx < CHX * 16; idx += 256) {
    int ci = idx >> 4, nn = idx & 15;
    const float* row = hb + ci * COLS + n0 + nn;
    ht[ci][nn]      = row[0];
    ht[ci][16 + nn] = row[256];
    ht[ci][32 + nn] = row[512];
  }
  __syncthreads();
  const int co = cohalf * 64 + (t >> 2);
  const int nn0 = (t & 3) * 4;
  float acc[3][4];
#pragma unroll
  for (int v = 0; v < 3; v++)
#pragma unroll
    for (int k = 0; k < 4; k++) acc[v][k] = 0.f;
  const float* w = Wffn2 + co * CHX;
  for (int ci = 0; ci < CHX; ci++) {
    float wv = w[ci];
#pragma unroll
    for (int v = 0; v < 3; v++)
#pragma unroll
      for (int k = 0; k < 4; k++)
        acc[v][k] = fmaf(wv, ht[ci][v * 16 + nn0 + k], acc[v][k]);
  }
  const float* st = stats + b * 12;
  const float g = gamma[co];
  const float* yb = y1 + (size_t)(b * CC + co) * COLS + n0 + nn0;
  const size_t base = (size_t)(b * CC + co) * COLS + n0 + nn0;
  float v9[9];
#pragma unroll
  for (int k = 0; k < 9; k++) v9[k] = 0.f;
#pragma unroll
  for (int k = 0; k < 4; k++) {
    float d0 = yb[k] - st[0], d1 = yb[256 + k] - st[1], d2 = yb[512 + k] - st[2];
    float x0 = g * (st[3] * d0 + st[4] * d1 + st[5] * d2) + acc[0][k];
    float x1 = g * (st[6] * d0 + st[7] * d1 + st[8] * d2) + acc[1][k];
    float xz = g * (st[9] * d0 + st[10] * d1 + st[11] * d2) + acc[2][k];
    x2[base + k]       = x0;
    x2[base + 256 + k] = x1;
    x2[base + 512 + k] = xz;
    v9[0] += x0; v9[1] += x1; v9[2] += xz;
    v9[3] += x0 * x0; v9[4] += x0 * x1; v9[5] += x0 * xz;
    v9[6] += x1 * x1; v9[7] += x1 * xz; v9[8] += xz * xz;
  }
#pragma unroll
  for (int off = 32; off >= 1; off >>= 1)
#pragma unroll
    for (int k = 0; k < 9; k++) v9[k] += __shfl_down(v9[k], off);
  __syncthreads();
  float* red = &ht[0][0];
  const int wid = t >> 6, lane = t & 63;
  if (lane == 0)
#pragma unroll
    for (int k = 0; k < 9; k++) red[wid * 9 + k] = v9[k];
  __syncthreads();
  if (t == 0)
#pragma unroll
    for (int k = 0; k < 9; k++)
      part[(size_t)(b * 32 + nt * 2 + cohalf) * 9 + k] =
          (red[k] + red[9 + k]) + (red[18 + k] + red[27 + k]);
}

// ---------------------------------------------------------------------------
// K8: final whitening apply -> out. grid (256), 256 thr. (r11)
// ---------------------------------------------------------------------------
__global__ __launch_bounds__(256) void k_zca_apply(
    const float* __restrict__ y, const float* __restrict__ stats,
    const float* __restrict__ gamma, float* __restrict__ out)
{
  int idx = blockIdx.x * blockDim.x + threadIdx.x;
  int b = idx >> 15, rem = idx & 32767;
  int cidx = rem >> 8, n = rem & 255;
  const float* st = stats + b * 12;
  const size_t base = (size_t)(b * CC + cidx) * COLS + n;
  float v0 = y[base] - st[0];
  float v1 = y[base + 256] - st[1];
  float v2 = y[base + 512] - st[2];
  float g = gamma[cidx];
  out[base]       = g * (st[3] * v0 + st[4] * v1 + st[5] * v2);
  out[base + 256] = g * (st[6] * v0 + st[7] * v1 + st[8] * v2);
  out[base + 512] = g * (st[9] * v0 + st[10] * v1 + st[11] * v2);
}

// ---------------------------------------------------------------------------
// Workspace: FULLY DISJOINT. QKV=196,608  RM=131,072  HB=393,216 floats.
// 9 launches: qkv, rel_w, attn, wo_res_p, fin, ffn1, ffn2_p, fin, apply.
// ---------------------------------------------------------------------------
extern "C" void kernel_launch(void* const* d_in, const int* in_sizes, int n_in,
                              void* d_out, int out_size, void* d_ws, size_t ws_size,
                              hipStream_t stream)
{
  (void)in_sizes; (void)n_in; (void)out_size; (void)ws_size;
  const float* x      = (const float*)d_in[0];
  const float* pos    = (const float*)d_in[1];
  const float* Wq     = (const float*)d_in[2];
  const float* Wk     = (const float*)d_in[3];
  const float* Wv     = (const float*)d_in[4];
  const float* Wo     = (const float*)d_in[5];
  const float* W1     = (const float*)d_in[6];
  const float* b1     = (const float*)d_in[7];
  const float* W2     = (const float*)d_in[8];
  // d_in[9] = b2 : dropped (softmax shift-invariant per channel)
  const float* gamma1 = (const float*)d_in[10];
  const float* Wfeat  = (const float*)d_in[11];
  const float* Wdir   = (const float*)d_in[12];
  const float* Wffn2  = (const float*)d_in[13];
  const float* gamma2 = (const float*)d_in[14];

  float* ws = (float*)d_ws;
  const size_t QKV = (size_t)BB * NN * CC * 3;   // 196,608
  const size_t RM  = (size_t)BB * NN * NN;       // 131,072
  const size_t HB  = (size_t)BB * CHX * COLS;    // 393,216

  float* q_t    = ws;
  float* k_nat  = q_t    + QKV;
  float* v_t3   = k_nat  + QKV;
  float* rm_all = v_t3   + QKV;
  float* rp_all = rm_all + RM;
  float* a_nat  = rp_all + RM;
  float* y1     = a_nat  + QKV;
  float* hbuf   = y1     + QKV;
  float* x2     = hbuf   + HB;
  float* stats1 = x2     + QKV;
  float* stats2 = stats1 + 64;
  float* part1  = stats2 + 64;          // 576 floats
  float* part2  = part1  + 640;         // 576 floats

  k_qkv<<<dim3(48, 3, BB), 256, 0, stream>>>(x, Wq, Wk, Wv, q_t, k_nat, v_t3);
  k_rel_w<<<dim3(NN, BB), 1024, 0, stream>>>(q_t, k_nat, pos, rm_all, rp_all);
  k_attn<<<dim3(NN, 2, BB), 256, 0, stream>>>(rm_all, rp_all, v_t3, W1, b1, W2, a_nat);
  k_wo_res_p<<<dim3(16, 2, BB), 256, 0, stream>>>(a_nat, Wo, x, y1, part1);
  k_zca_fin<<<BB, 64, 0, stream>>>(part1, stats1);
  k_ffn1<<<dim3(16, 4, BB), 256, 0, stream>>>(y1, stats1, gamma1, Wfeat, Wdir, hbuf);
  k_ffn2_p<<<dim3(16, 2, BB), 256, 0, stream>>>(hbuf, Wffn2, y1, stats1, gamma1, x2, part2);
  k_zca_fin<<<BB, 64, 0, stream>>>(part2, stats2);
  k_zca_apply<<<256, 256, 0, stream>>>(x2, stats2, gamma2, (float*)d_out);
}

// Round 18
// 101.217 us; speedup vs baseline: 1.0445x; 1.0388x over previous
//
#include <hip/hip_runtime.h>
#include <math.h>

// Problem constants (B=2, C=128, N=256, H=64, CH=256)
#define BB 2
#define CC 128
#define NN 256
#define HH 64
#define CHX 256
#define COLS 768           // 3*N flattened (v,n) columns
#define NEG_ATTN 0.2f
#define NEG_FFN 0.1f

typedef __attribute__((ext_vector_type(8))) short short8b;   // 8 bf16 (4 VGPRs)
typedef __attribute__((ext_vector_type(4))) float f32x4;

__device__ __forceinline__ unsigned bf16rne(float x) {
  unsigned u = __float_as_uint(x);
  return (u + 0x7fffu + ((u >> 16) & 1u)) >> 16;
}

// ---------------------------------------------------------------------------
// K1: q,k,v = Wq/Wk/Wv @ x in three layouts (r3 row-gather structure).
// grid (48 col-tiles of 16, 3 which, B), 256 threads
// ---------------------------------------------------------------------------
__global__ __launch_bounds__(256) void k_qkv(
    const float* __restrict__ x, const float* __restrict__ Wq,
    const float* __restrict__ Wk, const float* __restrict__ Wv,
    float* __restrict__ q_t, float* __restrict__ k_nat, float* __restrict__ v_t3)
{
  const int ct = blockIdx.x, which = blockIdx.y, b = blockIdx.z;
  const int col0 = ct * 16;
  __shared__ float xt[CC][16];
  const float* xb = x + (size_t)b * CC * COLS;
  for (int idx = threadIdx.x; idx < CC * 16; idx += 256) {
    int r = idx >> 4, cc = idx & 15;
    xt[r][cc] = xb[r * COLS + col0 + cc];
  }
  __syncthreads();
  const float* W = (which == 0) ? Wq : ((which == 1) ? Wk : Wv);
  const int co = threadIdx.x >> 1;
  const int cc0 = (threadIdx.x & 1) * 8;
  float acc[8];
#pragma unroll
  for (int k = 0; k < 8; k++) acc[k] = 0.f;
  const float* wrow = W + co * CC;
  for (int ci = 0; ci < CC; ci++) {
    float wv = wrow[ci];
#pragma unroll
    for (int k = 0; k < 8; k++) acc[k] = fmaf(wv, xt[ci][cc0 + k], acc[k]);
  }
#pragma unroll
  for (int k = 0; k < 8; k++) {
    int col = col0 + cc0 + k;
    int v = col >> 8, n = col & 255;
    float val = acc[k];
    if (which == 0)      q_t[((size_t)(b * NN + n) * CC + co) * 3 + v] = val;
    else if (which == 1) k_nat[(size_t)(b * CC + co) * COLS + col] = val;
    else                 v_t3[((size_t)(b * NN + n) * CC + co) * 3 + v] = val;
  }
}

// ---------------------------------------------------------------------------
// K1b: rel norms, WIDE: grid (N, B) x 1024 thr = full-chip occupancy.
// Thread (j = t&255, cq = t>>8) does 32 channels; LDS merge (fixed order).
// (r15-proven: 45 -> ~7 us vs low-occupancy variants)
// ---------------------------------------------------------------------------
__global__ __launch_bounds__(1024) void k_rel_w(
    const float* __restrict__ q_t, const float* __restrict__ k_nat,
    const float* __restrict__ pos, float* __restrict__ rm_all,
    float* __restrict__ rp_all)
{
  const int i = blockIdx.x, b = blockIdx.y;
  const int t = threadIdx.x;
  const int j = t & 255, cq = t >> 8;      // cq in 0..3
  __shared__ float qv[CC * 3];
  __shared__ float red[3][NN];
  for (int idx = t; idx < CC * 3; idx += 1024)
    qv[idx] = q_t[(size_t)(b * NN + i) * CC * 3 + idx];
  __syncthreads();
  const float* kb = k_nat + (size_t)b * CC * COLS + j;
  const int c0 = cq * 32;
  float s0 = 0.f, s1 = 0.f;
  for (int c = c0; c < c0 + 32; c += 2) {
    float kx0 = kb[c * COLS], ky0 = kb[c * COLS + 256], kz0 = kb[c * COLS + 512];
    float kx1 = kb[(c + 1) * COLS], ky1 = kb[(c + 1) * COLS + 256], kz1 = kb[(c + 1) * COLS + 512];
    float dx0 = kx0 - qv[c * 3], dy0 = ky0 - qv[c * 3 + 1], dz0 = kz0 - qv[c * 3 + 2];
    float dx1 = kx1 - qv[c * 3 + 3], dy1 = ky1 - qv[c * 3 + 4], dz1 = kz1 - qv[c * 3 + 5];
    float sq0 = dx0 * dx0 + dy0 * dy0 + dz0 * dz0;
    float sq1 = dx1 * dx1 + dy1 * dy1 + dz1 * dz1;
    s0 += (sq0 > 0.f) ? sqrtf(sq0) : 0.f;
    s1 += (sq1 > 0.f) ? sqrtf(sq1) : 0.f;
  }
  float s = s0 + s1;
  if (cq != 0) red[cq - 1][j] = s;
  __syncthreads();
  if (cq == 0) {
    float tot = ((s + red[0][j]) + (red[1][j] + red[2][j]));
    rm_all[(size_t)(b * NN + i) * NN + j] = tot * (1.f / 128.f);
    float dx = pos[(b * NN + i) * 3 + 0] - pos[(b * NN + j) * 3 + 0];
    float dy = pos[(b * NN + i) * 3 + 1] - pos[(b * NN + j) * 3 + 1];
    float dz = pos[(b * NN + i) * 3 + 2] - pos[(b * NN + j) * 3 + 2];
    float sq = dx * dx + dy * dy + dz * dz;
    rp_all[(size_t)(b * NN + i) * NN + j] = (sq > 0.f) ? sqrtf(sq) : 0.f;
  }
}

// ---------------------------------------------------------------------------
// K2: fused attention per (b, i, c-half). grid (N, 2, B), 256 threads.
// Score MLP via bf16 MFMA -> fp32 scores to padded LDS -> coalesced PV
// (c = lane, V as [n][c][3]: 12 contiguous B/lane). No running max
// (scores bounded: overflow needs s > 88 ~ 35 sigma). (r7/r11-proven)
// ---------------------------------------------------------------------------
__global__ __launch_bounds__(256, 4) void k_attn(
    const float* __restrict__ rm_all, const float* __restrict__ rp_all,
    const float* __restrict__ v_t3, const float* __restrict__ W1,
    const float* __restrict__ b1, const float* __restrict__ W2,
    float* __restrict__ a_nat)
{
  const int i = blockIdx.x, chalf = blockIdx.y, b = blockIdx.z;
  const int t = threadIdx.x;
  __shared__ __align__(16) short hh_s[64 * 64];   // bf16 bits, XOR-swizzled
  __shared__ __align__(16) short w2_s[64 * 64];   // bf16 bits, XOR-swizzled
  __shared__ float sc_s[64 * 65];                 // fp32 scores (padded)
  __shared__ float rm_s[NN], rp_s[NN];

  rm_s[t] = rm_all[(size_t)(b * NN + i) * NN + t];
  rp_s[t] = rp_all[(size_t)(b * NN + i) * NN + t];
  {
    const int cl = t >> 2, h0 = (t & 3) * 16;
    const float* wrow = W2 + (size_t)(chalf * 64 + cl) * HH + h0;
#pragma unroll
    for (int e = 0; e < 8; e++) {
      unsigned lo = bf16rne(wrow[2 * e]);
      unsigned hi = bf16rne(wrow[2 * e + 1]);
      int didx = (cl * 32 + (h0 >> 1) + e) ^ ((cl & 7) << 2);
      ((unsigned*)w2_s)[didx] = lo | (hi << 16);
    }
  }
  const int h2 = (t & 31) * 2, jgrp = t >> 5;
  const float4 w1v = *reinterpret_cast<const float4*>(W1 + 2 * h2);
  const float c0 = b1[h2], c1 = b1[h2 + 1];
  __syncthreads();

  auto phase2 = [&](int q) {
#pragma unroll
    for (int jj = 0; jj < 8; jj++) {
      int jl = jgrp * 8 + jj;
      int jg = q * 64 + jl;
      float rmv = rm_s[jg], rpv = rp_s[jg];
      float g0 = fmaf(w1v.x, rmv, fmaf(w1v.y, rpv, c0));
      float g1 = fmaf(w1v.z, rmv, fmaf(w1v.w, rpv, c1));
      g0 = (g0 >= 0.f) ? g0 : NEG_ATTN * g0;
      g1 = (g1 >= 0.f) ? g1 : NEG_ATTN * g1;
      int didx = (jl * 32 + (h2 >> 1)) ^ ((jl & 7) << 2);
      ((unsigned*)hh_s)[didx] = bf16rne(g0) | (bf16rne(g1) << 16);
    }
  };

  phase2(0);
  __syncthreads();

  const int lane = t & 63, wv = t >> 6;
  const int g8 = (lane >> 4) * 8;
  const int cdx = wv * 16 + (lane & 15);
  const short8b bfr0 = *reinterpret_cast<const short8b*>(&w2_s[(cdx * 64 + g8) ^ ((cdx & 7) << 3)]);
  const short8b bfr1 = *reinterpret_cast<const short8b*>(&w2_s[(cdx * 64 + 32 + g8) ^ ((cdx & 7) << 3)]);

  const int cl = lane;
  const int par = wv;
  const int vc = chalf * 64 + cl;
  float l = 0.f, a0 = 0.f, a1 = 0.f, a2 = 0.f;

  for (int q = 0; q < 4; q++) {
#pragma unroll
    for (int jt = 0; jt < 4; jt++) {
      int jr = jt * 16 + (lane & 15);
      short8b af0 = *reinterpret_cast<const short8b*>(&hh_s[(jr * 64 + g8) ^ ((jr & 7) << 3)]);
      short8b af1 = *reinterpret_cast<const short8b*>(&hh_s[(jr * 64 + 32 + g8) ^ ((jr & 7) << 3)]);
      f32x4 acc = {0.f, 0.f, 0.f, 0.f};
      acc = __builtin_amdgcn_mfma_f32_16x16x32_bf16(af0, bfr0, acc, 0, 0, 0);
      acc = __builtin_amdgcn_mfma_f32_16x16x32_bf16(af1, bfr1, acc, 0, 0, 0);
      int row0 = jt * 16 + (lane >> 4) * 4;
      int ccol = wv * 16 + (lane & 15);
#pragma unroll
      for (int r = 0; r < 4; r++) sc_s[(row0 + r) * 65 + ccol] = acc[r];
    }
    __syncthreads();
#pragma unroll 4
    for (int jj = 0; jj < 16; jj++) {
      int jl = jj * 4 + par;
      int jg = q * 64 + jl;
      float s = sc_s[jl * 65 + cl];
      const float* vb = v_t3 + ((size_t)(b * NN + jg) * CC + vc) * 3;
      float v0 = vb[0], v1 = vb[1], v2 = vb[2];
      float p = __expf(s);
      l += p;
      a0 = fmaf(p, v0, a0);
      a1 = fmaf(p, v1, a1);
      a2 = fmaf(p, v2, a2);
    }
    if (q < 3) phase2(q + 1);
    __syncthreads();
  }

  float* mrg = sc_s;
  if (par != 0) {
    float* mp = mrg + (cl * 3 + (par - 1)) * 4;
    mp[0] = l; mp[1] = a0; mp[2] = a1; mp[3] = a2;
  }
  __syncthreads();
  if (par == 0) {
    float L = l, A0 = a0, A1 = a1, A2 = a2;
#pragma unroll
    for (int q = 0; q < 3; q++) {
      const float* mp = mrg + (cl * 3 + q) * 4;
      L += mp[0]; A0 += mp[1]; A1 += mp[2]; A2 += mp[3];
    }
    float inv = 1.f / L;
    float* ap = a_nat + (size_t)(b * CC + vc) * COLS + i;
    ap[0] = A0 * inv; ap[256] = A1 * inv; ap[512] = A2 * inv;
  }
}

// ---------------------------------------------------------------------------
// K3: y1 = x + Wo @ a_nat.  grid (48 col-tiles of 16, 2 co-halves, B), 256 thr.
// ---------------------------------------------------------------------------
__global__ __launch_bounds__(256) void k_wo_res(
    const float* __restrict__ a_nat, const float* __restrict__ Wo,
    const float* __restrict__ x, float* __restrict__ y1)
{
  const int ct = blockIdx.x, cohalf = blockIdx.y, b = blockIdx.z;
  const int col0 = ct * 16;
  __shared__ float at[CC][16];
  const float* ab = a_nat + (size_t)b * CC * COLS;
  for (int idx = threadIdx.x; idx < CC * 16; idx += 256) {
    int r = idx >> 4, cc = idx & 15;
    at[r][cc] = ab[r * COLS + col0 + cc];
  }
  __syncthreads();
  const int co = cohalf * 64 + (threadIdx.x >> 2);
  const int cc0 = (threadIdx.x & 3) * 4;
  float acc[4];
#pragma unroll
  for (int k = 0; k < 4; k++) acc[k] = 0.f;
  const float* wrow = Wo + co * CC;
  for (int ci = 0; ci < CC; ci++) {
    float wv = wrow[ci];
#pragma unroll
    for (int k = 0; k < 4; k++) acc[k] = fmaf(wv, at[ci][cc0 + k], acc[k]);
  }
  const size_t base = (size_t)(b * CC + co) * COLS + col0 + cc0;
#pragma unroll
  for (int k = 0; k < 4; k++) y1[base + k] = x[base + k] + acc[k];
}

// ---------------------------------------------------------------------------
// K4: fused ZCA stats + 3x3 Jacobi + whitening matrix. grid (B), 1024 thr.
// ---------------------------------------------------------------------------
__global__ __launch_bounds__(1024) void k_stats(
    const float* __restrict__ y, float* __restrict__ stats)
{
  const int b = blockIdx.x;
  const float* yb = y + (size_t)b * CC * COLS;
  const int t = threadIdx.x;
  float v9[9];
#pragma unroll
  for (int k = 0; k < 9; k++) v9[k] = 0.f;
  for (int e = 0; e < 32; e++) {
    int idx = e * 1024 + t;
    int cidx = idx >> 8, n = idx & 255;
    const float* row = yb + cidx * COLS + n;
    float v0 = row[0], v1 = row[256], v2 = row[512];
    v9[0] += v0; v9[1] += v1; v9[2] += v2;
    v9[3] += v0 * v0; v9[4] += v0 * v1; v9[5] += v0 * v2;
    v9[6] += v1 * v1; v9[7] += v1 * v2; v9[8] += v2 * v2;
  }
#pragma unroll
  for (int off = 32; off >= 1; off >>= 1)
#pragma unroll
    for (int k = 0; k < 9; k++) v9[k] += __shfl_down(v9[k], off);
  __shared__ float red[16][9];
  const int wid = t >> 6, lane = t & 63;
  if (lane == 0)
#pragma unroll
    for (int k = 0; k < 9; k++) red[wid][k] = v9[k];
  __syncthreads();
  if (t == 0) {
    float tot[9];
#pragma unroll
    for (int k = 0; k < 9; k++) tot[k] = 0.f;
    for (int w = 0; w < 16; w++)
#pragma unroll
      for (int k = 0; k < 9; k++) tot[k] += red[w][k];
    const float M = (float)(CC * NN);
    float mu0 = tot[0] / M, mu1 = tot[1] / M, mu2 = tot[2] / M;
    float A[3][3];
    A[0][0] = (tot[3] - M * mu0 * mu0) / M + 1e-5f;
    A[0][1] = A[1][0] = (tot[4] - M * mu0 * mu1) / M;
    A[0][2] = A[2][0] = (tot[5] - M * mu0 * mu2) / M;
    A[1][1] = (tot[6] - M * mu1 * mu1) / M + 1e-5f;
    A[1][2] = A[2][1] = (tot[7] - M * mu1 * mu2) / M;
    A[2][2] = (tot[8] - M * mu2 * mu2) / M + 1e-5f;
    float V[3][3] = {{1.f, 0.f, 0.f}, {0.f, 1.f, 0.f}, {0.f, 0.f, 1.f}};
    for (int sweep = 0; sweep < 10; sweep++) {
      for (int pi = 0; pi < 3; pi++) {
        const int p = (pi == 2) ? 1 : 0;
        const int q = (pi == 0) ? 1 : 2;
        float apq = A[p][q];
        if (fabsf(apq) < 1e-30f) continue;
        float theta = (A[q][q] - A[p][p]) / (2.f * apq);
        float tt = 1.f / (fabsf(theta) + sqrtf(theta * theta + 1.f));
        if (theta < 0.f) tt = -tt;
        float cr = 1.f / sqrtf(tt * tt + 1.f);
        float sr = tt * cr;
        float app = A[p][p], aqq = A[q][q];
        A[p][p] = app - tt * apq;
        A[q][q] = aqq + tt * apq;
        A[p][q] = A[q][p] = 0.f;
        const int r = 3 - p - q;
        float arp = A[r][p], arq = A[r][q];
        A[r][p] = A[p][r] = cr * arp - sr * arq;
        A[r][q] = A[q][r] = sr * arp + cr * arq;
        for (int rr = 0; rr < 3; rr++) {
          float vrp = V[rr][p], vrq = V[rr][q];
          V[rr][p] = cr * vrp - sr * vrq;
          V[rr][q] = sr * vrp + cr * vrq;
        }
      }
    }
    float rs[3];
#pragma unroll
    for (int k = 0; k < 3; k++) rs[k] = rsqrtf(fmaxf(A[k][k], 1e-5f));
    float* st = stats + b * 12;
    st[0] = mu0; st[1] = mu1; st[2] = mu2;
    for (int u = 0; u < 3; u++)
      for (int v = 0; v < 3; v++) {
        float acc = 0.f;
        for (int k = 0; k < 3; k++) acc += V[u][k] * rs[k] * V[v][k];
        st[3 + u * 3 + v] = acc;
      }
  }
}

// ---------------------------------------------------------------------------
// K6: FFN1 with fused whitening on read. grid (16, 4, B), 256 thr.
// ---------------------------------------------------------------------------
__global__ __launch_bounds__(256) void k_ffn1(
    const float* __restrict__ y1, const float* __restrict__ stats,
    const float* __restrict__ gamma, const float* __restrict__ Wfeat,
    const float* __restrict__ Wdir, float* __restrict__ hout)
{
  const int nt = blockIdx.x, cs = blockIdx.y, b = blockIdx.z;
  const int n0 = nt * 16, co0 = cs * 64;
  __shared__ float xt[CC][48];  // [ci][v*16+nn], whitened
  const float* yb = y1 + (size_t)b * CC * COLS;
  const float* st = stats + b * 12;
  for (int idx = threadIdx.x; idx < CC * 16; idx += 256) {
    int ci = idx >> 4, nn = idx & 15;
    const float* row = yb + ci * COLS + n0 + nn;
    float d0 = row[0] - st[0], d1 = row[256] - st[1], d2 = row[512] - st[2];
    float g = gamma[ci];
    xt[ci][nn]      = g * (st[3] * d0 + st[4] * d1 + st[5] * d2);
    xt[ci][16 + nn] = g * (st[6] * d0 + st[7] * d1 + st[8] * d2);
    xt[ci][32 + nn] = g * (st[9] * d0 + st[10] * d1 + st[11] * d2);
  }
  __syncthreads();
  const int co = co0 + (threadIdx.x & 63);
  const int nn0 = (threadIdx.x >> 6) * 4;
  float p[3][4], d[3][4];
#pragma unroll
  for (int v = 0; v < 3; v++)
#pragma unroll
    for (int k = 0; k < 4; k++) { p[v][k] = 0.f; d[v][k] = 0.f; }
  const float* wf = Wfeat + co * CC;
  const float* wd = Wdir + co * CC;
  for (int ci = 0; ci < CC; ci++) {
    float a = wf[ci], bb = wd[ci];
#pragma unroll
    for (int v = 0; v < 3; v++)
#pragma unroll
      for (int k = 0; k < 4; k++) {
        float xv = xt[ci][v * 16 + nn0 + k];
        p[v][k] = fmaf(a, xv, p[v][k]);
        d[v][k] = fmaf(bb, xv, d[v][k]);
      }
  }
  float* hb = hout + (size_t)(b * CHX + co) * COLS;
#pragma unroll
  for (int k = 0; k < 4; k++) {
    float dot = p[0][k] * d[0][k] + p[1][k] * d[1][k] + p[2][k] * d[2][k];
    float dsq = d[0][k] * d[0][k] + d[1][k] * d[1][k] + d[2][k] * d[2][k];
    float coef = (dot >= 0.f) ? 0.f : (1.f - NEG_FFN) * dot / (dsq + 1e-6f);
#pragma unroll
    for (int v = 0; v < 3; v++)
      hb[v * 256 + n0 + nn0 + k] = p[v][k] - coef * d[v][k];
  }
}

// ---------------------------------------------------------------------------
// K7: x2 = whiten(y1) + Wffn2 @ h.  grid (48, 2, B), 256 thr.
// ---------------------------------------------------------------------------
__global__ __launch_bounds__(256) void k_ffn2(
    const float* __restrict__ h, const float* __restrict__ Wffn2,
    const float* __restrict__ y1, const float* __restrict__ stats,
    const float* __restrict__ gamma, float* __restrict__ x2)
{
  const int ct = blockIdx.x, cohalf = blockIdx.y, b = blockIdx.z;
  const int col0 = ct * 16;
  __shared__ float ht[CHX][16];
  const float* hb = h + (size_t)b * CHX * COLS;
  for (int idx = threadIdx.x; idx < CHX * 16; idx += 256) {
    int r = idx >> 4, cc = idx & 15;
    ht[r][cc] = hb[r * COLS + col0 + cc];
  }
  __syncthreads();
  const int co = cohalf * 64 + (threadIdx.x >> 2);
  const int cc0 = (threadIdx.x & 3) * 4;
  float acc[4];
#pragma unroll
  for (int k = 0; k < 4; k++) acc[k] = 0.f;
  const float* w = Wffn2 + co * CHX;
  for (int ci = 0; ci < CHX; ci++) {
    float wv = w[ci];
#pragma unroll
    for (int k = 0; k < 4; k++) acc[k] = fmaf(wv, ht[ci][cc0 + k], acc[k]);
  }
  const int col_base = col0 + cc0;
  const int v = col_base >> 8, n = col_base & 255;
  const float* st = stats + b * 12;
  const float* yb = y1 + (size_t)(b * CC + co) * COLS + n;
  const float g = gamma[co];
  const float w0 = st[3 + v * 3 + 0], w1 = st[3 + v * 3 + 1], w2 = st[3 + v * 3 + 2];
  const size_t base = (size_t)(b * CC + co) * COLS + col_base;
#pragma unroll
  for (int k = 0; k < 4; k++) {
    float d0 = yb[k] - st[0], d1 = yb[256 + k] - st[1], d2 = yb[512 + k] - st[2];
    float xw = g * (w0 * d0 + w1 * d1 + w2 * d2);
    x2[base + k] = xw + acc[k];
  }
}

// ---------------------------------------------------------------------------
// K8: final whitening apply -> out. grid (256), 256 thr.
// ---------------------------------------------------------------------------
__global__ __launch_bounds__(256) void k_zca_apply(
    const float* __restrict__ y, const float* __restrict__ stats,
    const float* __restrict__ gamma, float* __restrict__ out)
{
  int idx = blockIdx.x * blockDim.x + threadIdx.x;
  int b = idx >> 15, rem = idx & 32767;
  int cidx = rem >> 8, n = rem & 255;
  const float* st = stats + b * 12;
  const size_t base = (size_t)(b * CC + cidx) * COLS + n;
  float v0 = y[base] - st[0];
  float v1 = y[base + 256] - st[1];
  float v2 = y[base + 512] - st[2];
  float g = gamma[cidx];
  out[base]       = g * (st[3] * v0 + st[4] * v1 + st[5] * v2);
  out[base + 256] = g * (st[6] * v0 + st[7] * v1 + st[8] * v2);
  out[base + 512] = g * (st[9] * v0 + st[10] * v1 + st[11] * v2);
}

// ---------------------------------------------------------------------------
// Workspace: FULLY DISJOINT buffers. QKV=196,608  RM=131,072  HB=393,216
// Total = 6*QKV + 2*RM + HB + 128 floats = 7.0 MiB (ws = 256 MiB).
// Final configuration (r15-proven best: 101.8 us).
// ---------------------------------------------------------------------------
extern "C" void kernel_launch(void* const* d_in, const int* in_sizes, int n_in,
                              void* d_out, int out_size, void* d_ws, size_t ws_size,
                              hipStream_t stream)
{
  (void)in_sizes; (void)n_in; (void)out_size; (void)ws_size;
  const float* x      = (const float*)d_in[0];
  const float* pos    = (const float*)d_in[1];
  const float* Wq     = (const float*)d_in[2];
  const float* Wk     = (const float*)d_in[3];
  const float* Wv     = (const float*)d_in[4];
  const float* Wo     = (const float*)d_in[5];
  const float* W1     = (const float*)d_in[6];
  const float* b1     = (const float*)d_in[7];
  const float* W2     = (const float*)d_in[8];
  // d_in[9] = b2 : dropped (softmax shift-invariant per channel)
  const float* gamma1 = (const float*)d_in[10];
  const float* Wfeat  = (const float*)d_in[11];
  const float* Wdir   = (const float*)d_in[12];
  const float* Wffn2  = (const float*)d_in[13];
  const float* gamma2 = (const float*)d_in[14];

  float* ws = (float*)d_ws;
  const size_t QKV = (size_t)BB * NN * CC * 3;   // 196,608
  const size_t RM  = (size_t)BB * NN * NN;       // 131,072
  const size_t HB  = (size_t)BB * CHX * COLS;    // 393,216

  float* q_t    = ws;
  float* k_nat  = q_t    + QKV;
  float* v_t3   = k_nat  + QKV;
  float* rm_all = v_t3   + QKV;
  float* rp_all = rm_all + RM;
  float* a_nat  = rp_all + RM;
  float* y1     = a_nat  + QKV;
  float* hbuf   = y1     + QKV;
  float* x2     = hbuf   + HB;
  float* stats1 = x2     + QKV;
  float* stats2 = stats1 + 64;

  k_qkv<<<dim3(48, 3, BB), 256, 0, stream>>>(x, Wq, Wk, Wv, q_t, k_nat, v_t3);
  k_rel_w<<<dim3(NN, BB), 1024, 0, stream>>>(q_t, k_nat, pos, rm_all, rp_all);
  k_attn<<<dim3(NN, 2, BB), 256, 0, stream>>>(rm_all, rp_all, v_t3, W1, b1, W2, a_nat);
  k_wo_res<<<dim3(48, 2, BB), 256, 0, stream>>>(a_nat, Wo, x, y1);
  k_stats<<<BB, 1024, 0, stream>>>(y1, stats1);
  k_ffn1<<<dim3(16, 4, BB), 256, 0, stream>>>(y1, stats1, gamma1, Wfeat, Wdir, hbuf);
  k_ffn2<<<dim3(48, 2, BB), 256, 0, stream>>>(hbuf, Wffn2, y1, stats1, gamma1, x2);
  k_stats<<<BB, 1024, 0, stream>>>(x2, stats2);
  k_zca_apply<<<256, 256, 0, stream>>>(x2, stats2, gamma2, (float*)d_out);
}